// Round 1
// baseline (1783.109 us; speedup 1.0000x reference)
//
#include <hip/hip_runtime.h>

// GINEConv: out = (1+eps)*node_feat + segment_sum(relu(node_feat[src] + edge_feat), dst)
// N=50000, D=128, E=800000, fp32. edge_index arrives as int32 (harness converts).

#define D 128
#define DV 32  // float4 chunks per row

__global__ void init_out_kernel(const float4* __restrict__ nf,
                                const float* __restrict__ eps,
                                float4* __restrict__ out, int n4) {
    int i = blockIdx.x * blockDim.x + threadIdx.x;
    if (i >= n4) return;
    float s = 1.0f + eps[0];
    float4 v = nf[i];
    v.x *= s; v.y *= s; v.z *= s; v.w *= s;
    out[i] = v;
}

__global__ void edge_scatter_kernel(const float4* __restrict__ nf,
                                    const float4* __restrict__ ef,
                                    const int* __restrict__ src,
                                    const int* __restrict__ dst,
                                    float* __restrict__ out, int E_) {
    int t = blockIdx.x * blockDim.x + threadIdx.x;
    int e = t >> 5;        // 32 threads per edge (each thread: one float4 = 4 dims)
    int c = t & 31;
    if (e >= E_) return;
    int s = src[e];
    int d = dst[e];
    float4 a = ef[(size_t)e * DV + c];
    float4 b = nf[(size_t)s * DV + c];
    float4 m;
    m.x = fmaxf(a.x + b.x, 0.0f);
    m.y = fmaxf(a.y + b.y, 0.0f);
    m.z = fmaxf(a.z + b.z, 0.0f);
    m.w = fmaxf(a.w + b.w, 0.0f);
    float* o = out + (size_t)d * D + c * 4;
    atomicAdd(o + 0, m.x);
    atomicAdd(o + 1, m.y);
    atomicAdd(o + 2, m.z);
    atomicAdd(o + 3, m.w);
}

extern "C" void kernel_launch(void* const* d_in, const int* in_sizes, int n_in,
                              void* d_out, int out_size, void* d_ws, size_t ws_size,
                              hipStream_t stream) {
    const float* node_feat = (const float*)d_in[0];
    const int*   edge_index = (const int*)d_in[1];
    const float* edge_feat = (const float*)d_in[2];
    const float* eps = (const float*)d_in[3];
    float* out = (float*)d_out;

    int ND = in_sizes[0];          // N*D
    int E_ = in_sizes[1] / 2;      // edge count
    const int* src = edge_index;
    const int* dst = edge_index + E_;

    // Pass 1: out = (1+eps) * node_feat   (d_out arrives poisoned; full overwrite)
    int n4 = ND / 4;
    int b1 = 256;
    init_out_kernel<<<(n4 + b1 - 1) / b1, b1, 0, stream>>>(
        (const float4*)node_feat, eps, (float4*)out, n4);

    // Pass 2: scatter-add relu(node_feat[src] + edge_feat) into out[dst]
    long long total = (long long)E_ * DV;
    int b2 = 256;
    int g2 = (int)((total + b2 - 1) / b2);
    edge_scatter_kernel<<<g2, b2, 0, stream>>>(
        (const float4*)node_feat, (const float4*)edge_feat, src, dst, out, E_);
}

// Round 2
// 708.961 us; speedup vs baseline: 2.5151x; 2.5151x over previous
//
#include <hip/hip_runtime.h>

// GINEConv: out = (1+eps)*node_feat + segment_sum(relu(node_feat[src] + edge_feat), dst)
// N=50000, D=128, E=800000, fp32.
//
// Strategy (R1): avoid 102.4M fp32 atomics (write-through to HBM was the R0
// bottleneck: WRITE_SIZE 1.6GB, 76G atomics/s). Build CSR-by-dst in d_ws
// (histogram + single-block scan + scatter of edge ids), then one wave per
// destination node accumulates its incoming messages in registers and does a
// single coalesced write.

#define D 128
#define DV2 64   // float2 chunks per row

// ---------- fallback path (R0) ----------
__global__ void init_out_kernel(const float4* __restrict__ nf,
                                const float* __restrict__ eps,
                                float4* __restrict__ out, int n4) {
    int i = blockIdx.x * blockDim.x + threadIdx.x;
    if (i >= n4) return;
    float s = 1.0f + eps[0];
    float4 v = nf[i];
    v.x *= s; v.y *= s; v.z *= s; v.w *= s;
    out[i] = v;
}

__global__ void edge_scatter_kernel(const float4* __restrict__ nf,
                                    const float4* __restrict__ ef,
                                    const int* __restrict__ src,
                                    const int* __restrict__ dst,
                                    float* __restrict__ out, int E_) {
    int t = blockIdx.x * blockDim.x + threadIdx.x;
    int e = t >> 5;
    int c = t & 31;
    if (e >= E_) return;
    int s = src[e];
    int d = dst[e];
    float4 a = ef[(size_t)e * 32 + c];
    float4 b = nf[(size_t)s * 32 + c];
    float4 m;
    m.x = fmaxf(a.x + b.x, 0.0f);
    m.y = fmaxf(a.y + b.y, 0.0f);
    m.z = fmaxf(a.z + b.z, 0.0f);
    m.w = fmaxf(a.w + b.w, 0.0f);
    float* o = out + (size_t)d * D + c * 4;
    atomicAdd(o + 0, m.x);
    atomicAdd(o + 1, m.y);
    atomicAdd(o + 2, m.z);
    atomicAdd(o + 3, m.w);
}

// ---------- CSR build ----------
__global__ void histogram_kernel(const int* __restrict__ dst, int* __restrict__ deg, int E_) {
    int e = blockIdx.x * blockDim.x + threadIdx.x;
    if (e >= E_) return;
    atomicAdd(&deg[dst[e]], 1);
}

// Single-block exclusive scan over n counts. Writes offs[0..n] and cursor[0..n-1].
// deg may alias cursor (each element read before written by the same thread).
__global__ void scan_kernel(const int* __restrict__ deg, int* __restrict__ offs,
                            int* __restrict__ cursor, int n) {
    __shared__ int wsum[16];       // per-wave totals (1024 threads = 16 waves)
    __shared__ int sh_carry;
    __shared__ int sh_total;
    int t = threadIdx.x;
    int lane = t & 63;
    int w = t >> 6;
    if (t == 0) sh_carry = 0;
    __syncthreads();
    for (int base = 0; base < n; base += 1024) {
        int idx = base + t;
        int x = (idx < n) ? deg[idx] : 0;
        // wave-inclusive scan via shfl_up
        int v = x;
        #pragma unroll
        for (int off = 1; off < 64; off <<= 1) {
            int u = __shfl_up(v, off);
            if (lane >= off) v += u;
        }
        if (lane == 63) wsum[w] = v;
        __syncthreads();
        if (t == 0) {
            int r = 0;
            #pragma unroll
            for (int i = 0; i < 16; ++i) { int tv = wsum[i]; wsum[i] = r; r += tv; }
            sh_total = r;
        }
        __syncthreads();
        int c = sh_carry;
        int excl = wsum[w] + v - x;      // block-exclusive
        if (idx < n) {
            offs[idx] = c + excl;
            cursor[idx] = c + excl;
        }
        __syncthreads();
        if (t == 0) sh_carry = c + sh_total;
        __syncthreads();
    }
    if (t == 0) offs[n] = sh_carry;
}

__global__ void scatter_perm_kernel(const int* __restrict__ src, const int* __restrict__ dst,
                                    int* __restrict__ cursor,
                                    int* __restrict__ perm_src, int* __restrict__ perm_eid,
                                    int E_) {
    int e = blockIdx.x * blockDim.x + threadIdx.x;
    if (e >= E_) return;
    int d = dst[e];
    int pos = atomicAdd(&cursor[d], 1);
    perm_src[pos] = src[e];
    perm_eid[pos] = e;
}

// ---------- aggregation: one wave per destination node ----------
__global__ void aggregate_kernel(const float2* __restrict__ nf,
                                 const float2* __restrict__ ef,
                                 const int* __restrict__ offs,
                                 const int* __restrict__ perm_src,
                                 const int* __restrict__ perm_eid,
                                 const float* __restrict__ eps,
                                 float2* __restrict__ out, int n) {
    int wid = (blockIdx.x * blockDim.x + threadIdx.x) >> 6;
    int lane = threadIdx.x & 63;
    if (wid >= n) return;
    int start = offs[wid];
    int end   = offs[wid + 1];
    float accx = 0.0f, accy = 0.0f;
    int i = start;
    for (; i + 1 < end; i += 2) {
        int s0 = perm_src[i],     e0 = perm_eid[i];
        int s1 = perm_src[i + 1], e1 = perm_eid[i + 1];
        float2 a0 = ef[(size_t)e0 * DV2 + lane];
        float2 b0 = nf[(size_t)s0 * DV2 + lane];
        float2 a1 = ef[(size_t)e1 * DV2 + lane];
        float2 b1 = nf[(size_t)s1 * DV2 + lane];
        accx += fmaxf(a0.x + b0.x, 0.0f) + fmaxf(a1.x + b1.x, 0.0f);
        accy += fmaxf(a0.y + b0.y, 0.0f) + fmaxf(a1.y + b1.y, 0.0f);
    }
    if (i < end) {
        int s0 = perm_src[i], e0 = perm_eid[i];
        float2 a0 = ef[(size_t)e0 * DV2 + lane];
        float2 b0 = nf[(size_t)s0 * DV2 + lane];
        accx += fmaxf(a0.x + b0.x, 0.0f);
        accy += fmaxf(a0.y + b0.y, 0.0f);
    }
    float sc = 1.0f + eps[0];
    float2 self = nf[(size_t)wid * DV2 + lane];
    float2 o;
    o.x = sc * self.x + accx;
    o.y = sc * self.y + accy;
    out[(size_t)wid * DV2 + lane] = o;
}

extern "C" void kernel_launch(void* const* d_in, const int* in_sizes, int n_in,
                              void* d_out, int out_size, void* d_ws, size_t ws_size,
                              hipStream_t stream) {
    const float* node_feat = (const float*)d_in[0];
    const int*   edge_index = (const int*)d_in[1];
    const float* edge_feat = (const float*)d_in[2];
    const float* eps = (const float*)d_in[3];
    float* out = (float*)d_out;

    int ND = in_sizes[0];
    int N_ = ND / D;
    int E_ = in_sizes[1] / 2;
    const int* src = edge_index;
    const int* dst = edge_index + E_;

    size_t need = ((size_t)2 * N_ + 1 + (size_t)2 * E_) * sizeof(int);
    if (ws_size < need) {
        // fallback: R0 atomic path
        int n4 = ND / 4;
        init_out_kernel<<<(n4 + 255) / 256, 256, 0, stream>>>(
            (const float4*)node_feat, eps, (float4*)out, n4);
        long long total = (long long)E_ * 32;
        int g2 = (int)((total + 255) / 256);
        edge_scatter_kernel<<<g2, 256, 0, stream>>>(
            (const float4*)node_feat, (const float4*)edge_feat, src, dst, out, E_);
        return;
    }

    int* cursor   = (int*)d_ws;          // N ints (also used as deg histogram)
    int* offs     = cursor + N_;         // N+1 ints
    int* perm_src = offs + (N_ + 1);     // E ints
    int* perm_eid = perm_src + E_;       // E ints

    // 1. zero the histogram
    hipMemsetAsync(cursor, 0, (size_t)N_ * sizeof(int), stream);
    // 2. histogram of dst
    histogram_kernel<<<(E_ + 255) / 256, 256, 0, stream>>>(dst, cursor, E_);
    // 3. exclusive scan -> offs, cursor
    scan_kernel<<<1, 1024, 0, stream>>>(cursor, offs, cursor, N_);
    // 4. scatter edge ids into CSR order
    scatter_perm_kernel<<<(E_ + 255) / 256, 256, 0, stream>>>(
        src, dst, cursor, perm_src, perm_eid, E_);
    // 5. aggregate: one wave per node, register accumulate, single write
    int waves_per_block = 4;             // 256 threads
    int g = (N_ + waves_per_block - 1) / waves_per_block;
    aggregate_kernel<<<g, 256, 0, stream>>>(
        (const float2*)node_feat, (const float2*)edge_feat,
        offs, perm_src, perm_eid, eps, (float2*)out, N_);
}